// Round 7
// baseline (1117556.250 us; speedup 1.0000x reference)
//
#include <hip/hip_runtime.h>
#include <hip/hip_fp16.h>

// LSTM: B=128, T=500 (499 steps used), in=265 (padded 288), H=512, out=123.
// R7 = R6 with three fixes:
//  1. NEWX region sized for the swizzled tiles (500*8*10240B) -- R6 overflowed
//     into HALL, corrupting x for t>~450.
//  2. Race-free placement claim: returning ticket atomic (completes at LLC
//     before anything else), verdict = spin until sum(tickets)==256. No
//     separate barrier counter whose visibility could outrun the tickets.
//  3. __launch_bounds__(512,1): R6's (512,2) capped VGPRs at 128 < ~140 live.

typedef _Float16 f16;
typedef _Float16 f16x8 __attribute__((ext_vector_type(8)));
typedef float f32x4 __attribute__((ext_vector_type(4)));

#define TS 499

// ---- ws layout (bytes) ----
#define NEWX_OFF   0ul
#define NEWX_BYTES (500ul*8*10240)       // swizzled x tiles: (t,bt) -> 10240B
#define HALL_OFF   (NEWX_OFF + NEWX_BYTES)
#define HALL_BYTES (500ul*128*512*2)
#define WHH_OFF    (HALL_OFF + HALL_BYTES)
#define WHH_BYTES  (2048ul*512*2)
#define WIH_OFF    (WHH_OFF + WHH_BYTES)
#define WIH_BYTES  (2048ul*288*2)
#define WFC_OFF    (WIH_OFF + WIH_BYTES)
#define WFC_BYTES  (128ul*512*2)
#define BIAS_OFF   (WFC_OFF + WFC_BYTES)
#define BIAS_BYTES (2048ul*4)
#define CNT_OFF    (BIAS_OFF + BIAS_BYTES)
// cnt u32: [8..15] per-XCD tickets   [512 + tile*32 + hs] step flags
#define CNT_BYTES  (4096ul)
#define WS_NEED    (CNT_OFF + CNT_BYTES)

__device__ __forceinline__ float tanh_dev(float x) {
    float ax = fabsf(x);
    float e  = __expf(-2.f * ax);
    float r  = (1.f - e) / (1.f + e);
    return copysignf(r, x);
}
__device__ __forceinline__ float sigm_dev(float x) {
    float e = __expf(-fabsf(x));
    float p = 1.f / (1.f + e);
    return x >= 0.f ? p : 1.f - p;
}

// ---- coherence helpers ----
__device__ __forceinline__ void llc_store_u32(unsigned* p, unsigned v) {
    asm volatile("global_store_dword %0, %1, off sc0 sc1\n\ts_waitcnt vmcnt(0)"
                 :: "v"(p), "v"(v) : "memory");
}
__device__ __forceinline__ void l2_store_u32(unsigned* p, unsigned v) {
    asm volatile("global_store_dword %0, %1, off sc0\n\ts_waitcnt vmcnt(0)"
                 :: "v"(p), "v"(v) : "memory");
}
__device__ __forceinline__ unsigned llc_load_u32(const unsigned* p) {
    unsigned v;
    asm volatile("global_load_dword %0, %1, off sc0 sc1\n\ts_waitcnt vmcnt(0)"
                 : "=v"(v) : "v"(p) : "memory");
    return v;
}
__device__ __forceinline__ unsigned l2_load_u32(const unsigned* p) {
    unsigned v;
    asm volatile("global_load_dword %0, %1, off sc0\n\ts_waitcnt vmcnt(0)"
                 : "=v"(v) : "v"(p) : "memory");
    return v;
}
// returning device-scope atomic add; complete (and globally visible) on return
__device__ __forceinline__ unsigned llc_atomic_add_ret(unsigned* p, unsigned v) {
    unsigned r;
    asm volatile("global_atomic_add %0, %1, %2, off sc0 sc1\n\ts_waitcnt vmcnt(0)"
                 : "=v"(r) : "v"(p), "v"(v) : "memory");
    return r;
}

// ---------------- phase 1a: new_x, written PRE-SWIZZLED per 16-row tile ----------------
// tile (t,bt): 16 rows x 640B; element k of row r at
// r*640 + (((k>>3) ^ (r&7))<<4) + (k&7)*2 -> linear LDS copy + XOR read = conflict-free.
__global__ void __launch_bounds__(256) prep_newx(const float* __restrict__ x,
                                                 f16* __restrict__ newx) {
    const int t  = blockIdx.x;      // 0..498
    const int bt = blockIdx.y;      // 0..7
    const int tid = threadIdx.x;
    char* tb = (char*)newx + ((size_t)t * 8 + bt) * 10240;
    for (int idx = tid; idx < 16 * 288; idx += 256) {
        const int r = idx / 288, k = idx - r * 288;
        const float* xr = x + ((size_t)(bt * 16 + r) * 500 + t) * 248;
        float v;
        if (k < 246)      v = tanh_dev(xr[k]);
        else if (k < 257) v = (k - 246 == (int)xr[247]) ? 0.76159415595576485f : 0.f;
        else if (k < 265) v = (k - 257 == (int)xr[246]) ? 0.76159415595576485f : 0.f;
        else              v = 0.f;
        const int byte = r * 640 + ((((k >> 3) ^ (r & 7)) << 4) | ((k & 7) << 1));
        *(f16*)(tb + byte) = (f16)v;
    }
}

// ---------------- phase 1b: weights -> f16 (padded), bias combine ----------------
__global__ void __launch_bounds__(256) prep_w(const float* __restrict__ W_ih,
                                              const float* __restrict__ W_hh,
                                              const float* __restrict__ W_fc,
                                              const float* __restrict__ b_ih,
                                              const float* __restrict__ b_hh,
                                              f16* __restrict__ whh, f16* __restrict__ wih,
                                              f16* __restrict__ wfc, float* __restrict__ bias) {
    const int NHH = 2048 * 512;
    const int NIH = 2048 * 288;
    const int NFC = 128 * 512;
    const int NT  = NHH + NIH + NFC + 2048;
    for (int i = blockIdx.x * 256 + threadIdx.x; i < NT; i += gridDim.x * 256) {
        if (i < NHH) {
            whh[i] = (f16)W_hh[i];
        } else if (i < NHH + NIH) {
            int j2 = i - NHH; int rr = j2 / 288, kk = j2 % 288;
            wih[j2] = (kk < 265) ? (f16)W_ih[rr * 265 + kk] : (f16)0.f;
        } else if (i < NHH + NIH + NFC) {
            int j2 = i - (NHH + NIH); int rr = j2 >> 9, kk = j2 & 511;
            wfc[j2] = (rr < 123) ? (f16)W_fc[rr * 512 + kk] : (f16)0.f;
        } else {
            int j2 = i - (NHH + NIH + NFC);
            bias[j2] = b_ih[j2] + b_hh[j2];
        }
    }
}

// ---------------- phase 2 main loop ----------------
// WG = 512 threads = 8 waves. wave w: gate g = w&3, col-block cb = w>>2.
// WG owns h-cols hsl*32 .. +31 (gate cols g*512 + hsl*32 + cb*16 + lane&15).
template <int UNI>
__device__ __forceinline__ void lstm_loop(const char* __restrict__ newx,
                                          f16* __restrict__ hall,
                                          unsigned* flags,
                                          const f16x8 (&wh)[16], const f16x8 (&wi)[9],
                                          float bb, int btile, int hsl, int tid,
                                          char* hsb, char* xsb, float* gf) {
    const int wl = tid & 63;
    const int arow = wl & 15, kgrp = wl >> 4;
    const int w  = tid >> 6;
    const int g  = w & 3, cb = w >> 2;
    const int bE = tid >> 5, colE = tid & 31;          // elementwise identity
    float c_st = 0.f;

    // prologue: x(0) into regs
    uint4 xra, xrb;
    {
        const char* xt = newx + (size_t)btile * 10240;
        xra = *(const uint4*)(xt + tid * 16);
        if (tid < 128) xrb = *(const uint4*)(xt + 8192 + tid * 16);
    }

    unsigned* const myflag = flags + hsl;
    const int row1 = tid >> 6;            // h-tile row (0..7); +8 for second half
    const int c16w = tid & 63;
    const int hw1 = row1 * 1024 + ((c16w ^ (row1 & 7)) << 4);
    const int hw2 = (row1 + 8) * 1024 + ((c16w ^ (row1 & 7)) << 4);

    for (int t = 0; t < TS; ++t) {
        // ---- 1. wave0 polls the tile's 16-flag line; others park at the barrier
        if (t > 0) {
            if (tid < 64) {
                int spins = 0;
                for (;;) {
                    unsigned f = (unsigned)t;
                    if (tid < 16) f = UNI ? l2_load_u32(flags + tid)
                                          : llc_load_u32(flags + tid);
                    if (__ballot(f >= (unsigned)t) == ~0ull) break;
                    __builtin_amdgcn_s_sleep(1);
                    if (++spins > (1 << 15)) break;   // degrade, never hang
                }
            }
        }
        __syncthreads();

        // ---- 2. stage h(t-1) (coherent) and x(t) (from regs) into LDS
        if (t > 0) {
            const char* hp0 = (const char*)(hall + ((size_t)(t - 1) * 128 + btile * 16) * 512)
                              + tid * 16;
            const char* hp1 = hp0 + 8192;
            uint4 h0, h1;
            if constexpr (UNI)
                asm volatile("global_load_dwordx4 %0, %2, off sc0\n\t"
                             "global_load_dwordx4 %1, %3, off sc0\n\t"
                             "s_waitcnt vmcnt(0)"
                             : "=&v"(h0), "=&v"(h1) : "v"(hp0), "v"(hp1) : "memory");
            else
                asm volatile("global_load_dwordx4 %0, %2, off sc0 sc1\n\t"
                             "global_load_dwordx4 %1, %3, off sc0 sc1\n\t"
                             "s_waitcnt vmcnt(0)"
                             : "=&v"(h0), "=&v"(h1) : "v"(hp0), "v"(hp1) : "memory");
            *(uint4*)(hsb + hw1) = h0;
            *(uint4*)(hsb + hw2) = h1;
        }
        *(uint4*)(xsb + tid * 16) = xra;
        if (tid < 128) *(uint4*)(xsb + 8192 + tid * 16) = xrb;
        __syncthreads();

        // ---- 3. fragments + MFMA
        f32x4 acc = {bb, bb, bb, bb};
        const int swq = arow & 7;
        #pragma unroll
        for (int kc = 0; kc < 9; ++kc) {
            f16x8 a = *(const f16x8*)(xsb + arow * 640 + (((kc * 4 + kgrp) ^ swq) << 4));
            acc = __builtin_amdgcn_mfma_f32_16x16x32_f16(a, wi[kc], acc, 0, 0, 0);
        }
        if (t > 0) {
            f32x4 e0 = {0.f, 0.f, 0.f, 0.f}, e1 = {0.f, 0.f, 0.f, 0.f};
            #pragma unroll
            for (int kc = 0; kc < 16; kc += 2) {
                f16x8 a0 = *(const f16x8*)(hsb + arow * 1024 + (((kc * 4 + kgrp) ^ swq) << 4));
                f16x8 a1 = *(const f16x8*)(hsb + arow * 1024 + ((((kc + 1) * 4 + kgrp) ^ swq) << 4));
                e0 = __builtin_amdgcn_mfma_f32_16x16x32_f16(a0, wh[kc],     e0, 0, 0, 0);
                e1 = __builtin_amdgcn_mfma_f32_16x16x32_f16(a1, wh[kc + 1], e1, 0, 0, 0);
            }
            acc += e0; acc += e1;
        }

        // ---- 4. prefetch x(t+1) into regs (plain cached loads; compiler-tracked)
        {
            const char* xt1 = newx + ((size_t)(t + 1) * 8 + btile) * 10240;
            xra = *(const uint4*)(xt1 + tid * 16);
            if (tid < 128) xrb = *(const uint4*)(xt1 + 8192 + tid * 16);
        }

        // ---- 5. gates -> LDS [4][16][32] f32
        {
            float* gp = gf + g * 512 + cb * 16 + (wl & 15);
            const int b4 = (wl >> 4) * 4;
            gp[(b4 + 0) * 32] = acc[0];
            gp[(b4 + 1) * 32] = acc[1];
            gp[(b4 + 2) * 32] = acc[2];
            gp[(b4 + 3) * 32] = acc[3];
        }
        __syncthreads();

        // ---- 6. elementwise LSTM cell (thread owns (bE, colE))
        {
            const float* gq = gf + bE * 32 + colE;
            float iv = sigm_dev(gq[0]);
            float fv = sigm_dev(gq[512]);
            float gv = tanh_dev(gq[1024]);
            float ov = sigm_dev(gq[1536]);
            c_st = fv * c_st + iv * gv;
            float hv = ov * tanh_dev(c_st);
            f16 hv16 = (f16)hv;
            unsigned u32v = (unsigned)__builtin_bit_cast(unsigned short, hv16);
            const f16* sp = hall + ((size_t)t * 128 + btile * 16 + bE) * 512 + hsl * 32 + colE;
            if constexpr (UNI)
                asm volatile("global_store_short %0, %1, off sc0" :: "v"(sp), "v"(u32v) : "memory");
            else
                asm volatile("global_store_short %0, %1, off sc0 sc1" :: "v"(sp), "v"(u32v) : "memory");
        }
        asm volatile("s_waitcnt vmcnt(0)" ::: "memory");  // h committed at coherence point
        __syncthreads();                                   // all waves' stores done
        if (tid == 0) {
            if constexpr (UNI) l2_store_u32(myflag, (unsigned)(t + 1));
            else               llc_store_u32(myflag, (unsigned)(t + 1));
        }
    }
}

__global__ void __launch_bounds__(512, 1) lstm_seq(const f16* __restrict__ newx,
                                                   f16* __restrict__ hall,
                                                   const f16* __restrict__ whh,
                                                   const f16* __restrict__ wih,
                                                   const float* __restrict__ bias,
                                                   unsigned* __restrict__ cnt) {
    __shared__ __align__(16) char hsb[16 * 1024];
    __shared__ __align__(16) char xsb[16 * 640];
    __shared__ float gf[4 * 16 * 32];
    __shared__ int ticket_sh, uni_sh;

    const int tid = threadIdx.x, bid = blockIdx.x;

    unsigned xcd;
    asm volatile("s_getreg_b32 %0, hwreg(HW_REG_XCC_ID)" : "=s"(xcd));
    xcd &= 7u;

    unsigned* tk = cnt + 8;   // [8..15] per-XCD tickets

    // --- one-time claim; verdict when sum(tickets)==256 (race-free: each WG's
    // ticket add is COMPLETE at the LLC before it can contribute to any sum) ---
    if (tid == 0) {
        ticket_sh = (int)llc_atomic_add_ret(&tk[xcd], 1u);
        int spins = 0;
        for (;;) {
            unsigned s = 0;
            for (int x8 = 0; x8 < 8; ++x8) s += llc_load_u32(&tk[x8]);
            if (s >= 256u) break;
            __builtin_amdgcn_s_sleep(16);
            if (++spins > (1 << 20)) break;   // degrade, never hang
        }
        int ok = 1;
        for (int x8 = 0; x8 < 8; ++x8) ok &= (llc_load_u32(&tk[x8]) >= 16u) ? 1 : 0;
        uni_sh = ok;
    }
    __syncthreads();
    const bool uni = uni_sh != 0;
    const int ticket = ticket_sh;

    int btile, hsl, active;
    if (uni) { btile = (int)xcd; hsl = ticket;   active = (ticket < 16); }
    else     { btile = bid & 7;  hsl = bid >> 3; active = (bid < 128); }
    if (!active) return;

    // wave identity + weight fragments in registers
    const int w = tid >> 6, wl = tid & 63;
    const int arow = wl & 15, kgrp = wl >> 4;
    const int g = w & 3, cb = w >> 2;
    const int grow = g * 512 + hsl * 32 + cb * 16 + arow;

    f16x8 wh[16], wi[9];
    #pragma unroll
    for (int kc = 0; kc < 16; ++kc)
        wh[kc] = *(const f16x8*)(whh + (size_t)grow * 512 + kc * 32 + kgrp * 8);
    #pragma unroll
    for (int kc = 0; kc < 9; ++kc)
        wi[kc] = *(const f16x8*)(wih + (size_t)grow * 288 + kc * 32 + kgrp * 8);
    const float bb = bias[grow];

    unsigned* flags = cnt + 512 + btile * 32;

    if (uni)
        lstm_loop<1>((const char*)newx, hall, flags, wh, wi, bb, btile, hsl, tid, hsb, xsb, gf);
    else
        lstm_loop<0>((const char*)newx, hall, flags, wh, wi, bb, btile, hsl, tid, hsb, xsb, gf);
}

// ---------------- phase 3: out = sigmoid(h_all @ W_fc^T + b_fc) ----------------
__global__ void __launch_bounds__(256) out_gemm(const f16* __restrict__ hall,
                                                const f16* __restrict__ wfc,
                                                const float* __restrict__ bfc,
                                                float* __restrict__ out) {
    const int tid = threadIdx.x;
    const int w = tid >> 6, wl = tid & 63;
    const int arow = wl & 15, kgrp = wl >> 4;
    const long m0 = (long)blockIdx.x * 64 + w * 16;
    const f16* ap = hall + (m0 + arow) * 512 + kgrp * 8;
    f16x8 a[16];
    #pragma unroll
    for (int kc = 0; kc < 16; ++kc) a[kc] = *(const f16x8*)(ap + kc * 32);
    #pragma unroll
    for (int jt = 0; jt < 8; ++jt) {
        f32x4 acc = {0.f, 0.f, 0.f, 0.f};
        const f16* bp = wfc + (size_t)(jt * 16 + arow) * 512 + kgrp * 8;
        #pragma unroll
        for (int kc = 0; kc < 16; ++kc)
            acc = __builtin_amdgcn_mfma_f32_16x16x32_f16(a[kc], *(const f16x8*)(bp + kc * 32),
                                                         acc, 0, 0, 0);
        const int col = jt * 16 + arow;        // D col = lane&15
        if (col < 123) {
            const float bv = bfc[col];
            #pragma unroll
            for (int rr = 0; rr < 4; ++rr) {
                long m = m0 + kgrp * 4 + rr;   // D row = (lane>>4)*4 + reg
                int tt = (int)(m >> 7), b = (int)(m & 127);
                out[((size_t)b * 499 + tt) * 123 + col] = sigm_dev(acc[rr] + bv);
            }
        }
    }
}

extern "C" void kernel_launch(void* const* d_in, const int* in_sizes, int n_in,
                              void* d_out, int out_size, void* d_ws, size_t ws_size,
                              hipStream_t stream) {
    if (ws_size < WS_NEED) return;   // safe no-op rather than OOB writes

    const float* x    = (const float*)d_in[0];
    const float* W_ih = (const float*)d_in[1];
    const float* W_hh = (const float*)d_in[2];
    const float* b_ih = (const float*)d_in[3];
    const float* b_hh = (const float*)d_in[4];
    const float* W_fc = (const float*)d_in[5];
    const float* b_fc = (const float*)d_in[6];
    float* out = (float*)d_out;
    char* ws = (char*)d_ws;

    f16* newx   = (f16*)(ws + NEWX_OFF);
    f16* hall   = (f16*)(ws + HALL_OFF);
    f16* whh    = (f16*)(ws + WHH_OFF);
    f16* wih    = (f16*)(ws + WIH_OFF);
    f16* wfc    = (f16*)(ws + WFC_OFF);
    float* bias = (float*)(ws + BIAS_OFF);
    unsigned* cnt = (unsigned*)(ws + CNT_OFF);

    // counters/flags must be 0 at the start of every call (replays don't re-poison)
    hipMemsetAsync(cnt, 0, CNT_BYTES, stream);

    prep_newx<<<dim3(TS, 8), 256, 0, stream>>>(x, newx);
    prep_w<<<512, 256, 0, stream>>>(W_ih, W_hh, W_fc, b_ih, b_hh, whh, wih, wfc, bias);

    void* args[6] = {&newx, &hall, &whh, &wih, &bias, &cnt};
    hipLaunchCooperativeKernel((const void*)lstm_seq, dim3(256), dim3(512), args,
                               0, stream);

    out_gemm<<<998, 256, 0, stream>>>(hall, wfc, b_fc, out);
}

// Round 9
// 1541.340 us; speedup vs baseline: 725.0550x; 725.0550x over previous
//
#include <hip/hip_runtime.h>
#include <hip/hip_fp16.h>

// LSTM: B=128, T=500 (499 steps used), in=265 (padded 288), H=512, out=123.
// R9 = R8 with the asm operand fix: 128-bit asm operands must be
// ext_vector_type (passed directly in VGPRs), not HIP's uint4 struct
// (passed indirectly -> "indirect register inputs" compile error).
// Scheme: LLC-only sync. 128 WGs x 512 threads: tile = bid&7 (16 batch rows),
// slice hsl = bid>>3 (32 h-cols). Per step: all-wave 64B flag-line poll ->
// coherent h stage into swizzled LDS -> MFMA -> gates via LDS -> elementwise
// -> wave0 packs 64x16B coherent stores + single vmcnt ack + flag store.

typedef _Float16 f16;
typedef _Float16 f16x8 __attribute__((ext_vector_type(8)));
typedef float f32x4 __attribute__((ext_vector_type(4)));
typedef unsigned u32x4 __attribute__((ext_vector_type(4)));

#define TS 499

// ---- ws layout (bytes) ----
#define NEWX_OFF   0ul
#define NEWX_BYTES (500ul*8*10240)       // swizzled x tiles: (t,bt) -> 10240B
#define HALL_OFF   (NEWX_OFF + NEWX_BYTES)
#define HALL_BYTES (500ul*128*512*2)
#define WHH_OFF    (HALL_OFF + HALL_BYTES)
#define WHH_BYTES  (2048ul*512*2)
#define WIH_OFF    (WHH_OFF + WHH_BYTES)
#define WIH_BYTES  (2048ul*288*2)
#define WFC_OFF    (WIH_OFF + WIH_BYTES)
#define WFC_BYTES  (128ul*512*2)
#define BIAS_OFF   (WFC_OFF + WFC_BYTES)
#define BIAS_BYTES (2048ul*4)
#define CNT_OFF    (BIAS_OFF + BIAS_BYTES)
// cnt u32: [512 + tile*32 + hsl] step flags (tile flag line = 64B, 128B pitch)
#define CNT_BYTES  (4096ul)
#define WS_NEED    (CNT_OFF + CNT_BYTES)

__device__ __forceinline__ float tanh_dev(float x) {
    float ax = fabsf(x);
    float e  = __expf(-2.f * ax);
    float r  = (1.f - e) / (1.f + e);
    return copysignf(r, x);
}
__device__ __forceinline__ float sigm_dev(float x) {
    float e = __expf(-fabsf(x));
    float p = 1.f / (1.f + e);
    return x >= 0.f ? p : 1.f - p;
}

// flag store: fire-and-forget device-coherent (no ack wait needed)
__device__ __forceinline__ void llc_store_nowait(unsigned* p, unsigned v) {
    asm volatile("global_store_dword %0, %1, off sc0 sc1" :: "v"(p), "v"(v) : "memory");
}
__device__ __forceinline__ unsigned llc_load_u32(const unsigned* p) {
    unsigned v;
    asm volatile("global_load_dword %0, %1, off sc0 sc1\n\ts_waitcnt vmcnt(0)"
                 : "=v"(v) : "v"(p) : "memory");
    return v;
}

// ---------------- phase 1a: new_x, written PRE-SWIZZLED per 16-row tile ----------------
// tile (t,bt): 16 rows x 640B; element k of row r at
// r*640 + (((k>>3) ^ (r&7))<<4) + (k&7)*2 -> linear LDS copy + XOR read = conflict-free.
__global__ void __launch_bounds__(256) prep_newx(const float* __restrict__ x,
                                                 f16* __restrict__ newx) {
    const int t  = blockIdx.x;      // 0..498
    const int bt = blockIdx.y;      // 0..7
    const int tid = threadIdx.x;
    char* tb = (char*)newx + ((size_t)t * 8 + bt) * 10240;
    for (int idx = tid; idx < 16 * 288; idx += 256) {
        const int r = idx / 288, k = idx - r * 288;
        const float* xr = x + ((size_t)(bt * 16 + r) * 500 + t) * 248;
        float v;
        if (k < 246)      v = tanh_dev(xr[k]);
        else if (k < 257) v = (k - 246 == (int)xr[247]) ? 0.76159415595576485f : 0.f;
        else if (k < 265) v = (k - 257 == (int)xr[246]) ? 0.76159415595576485f : 0.f;
        else              v = 0.f;
        const int byte = r * 640 + ((((k >> 3) ^ (r & 7)) << 4) | ((k & 7) << 1));
        *(f16*)(tb + byte) = (f16)v;
    }
}

// ---------------- phase 1b: weights -> f16 (padded), bias combine ----------------
__global__ void __launch_bounds__(256) prep_w(const float* __restrict__ W_ih,
                                              const float* __restrict__ W_hh,
                                              const float* __restrict__ W_fc,
                                              const float* __restrict__ b_ih,
                                              const float* __restrict__ b_hh,
                                              f16* __restrict__ whh, f16* __restrict__ wih,
                                              f16* __restrict__ wfc, float* __restrict__ bias) {
    const int NHH = 2048 * 512;
    const int NIH = 2048 * 288;
    const int NFC = 128 * 512;
    const int NT  = NHH + NIH + NFC + 2048;
    for (int i = blockIdx.x * 256 + threadIdx.x; i < NT; i += gridDim.x * 256) {
        if (i < NHH) {
            whh[i] = (f16)W_hh[i];
        } else if (i < NHH + NIH) {
            int j2 = i - NHH; int rr = j2 / 288, kk = j2 % 288;
            wih[j2] = (kk < 265) ? (f16)W_ih[rr * 265 + kk] : (f16)0.f;
        } else if (i < NHH + NIH + NFC) {
            int j2 = i - (NHH + NIH); int rr = j2 >> 9, kk = j2 & 511;
            wfc[j2] = (rr < 123) ? (f16)W_fc[rr * 512 + kk] : (f16)0.f;
        } else {
            int j2 = i - (NHH + NIH + NFC);
            bias[j2] = b_ih[j2] + b_hh[j2];
        }
    }
}

// ---------------- phase 2: persistent sequential LSTM ----------------
// WG = 512 threads = 8 waves. wave w: gate g = w&3, col-block cb = w>>2.
// WG owns h-cols hsl*32..+31 (gate cols g*512 + hsl*32 + cb*16 + lane&15).
__global__ void __launch_bounds__(512, 1) lstm_seq(const f16* __restrict__ newx_,
                                                   f16* __restrict__ hall,
                                                   const f16* __restrict__ whh,
                                                   const f16* __restrict__ wih,
                                                   const float* __restrict__ bias,
                                                   unsigned* __restrict__ cnt) {
    __shared__ __align__(16) char hsb[16 * 1024];   // h(t-1) tile, XOR-swizzled
    __shared__ __align__(16) char xsb[16 * 640];    // x(t) tile (pre-swizzled)
    __shared__ float gf[4 * 16 * 32];               // gates [gate][row][col]
    __shared__ __align__(16) f16 hout[512];         // this WG's h slice [row][32 cols]

    const char* newx = (const char*)newx_;
    const int tid = threadIdx.x, bid = blockIdx.x;
    const int btile = bid & 7;
    const int hsl   = bid >> 3;          // 0..15

    const int w = tid >> 6, wl = tid & 63;
    const int arow = wl & 15, kgrp = wl >> 4;
    const int g = w & 3, cb = w >> 2;
    const int grow = g * 512 + hsl * 32 + cb * 16 + arow;
    const int bE = tid >> 5, colE = tid & 31;    // elementwise identity

    // weight fragments (B operand): K=512 for W_hh, K=288 for W_ih
    f16x8 wh[16], wi[9];
    #pragma unroll
    for (int kc = 0; kc < 16; ++kc)
        wh[kc] = *(const f16x8*)(whh + (size_t)grow * 512 + kc * 32 + kgrp * 8);
    #pragma unroll
    for (int kc = 0; kc < 9; ++kc)
        wi[kc] = *(const f16x8*)(wih + (size_t)grow * 288 + kc * 32 + kgrp * 8);
    const float bb = bias[grow];

    unsigned* const flags  = cnt + 512 + btile * 32;
    unsigned* const myflag = flags + hsl;

    // h-staging identities (verified mapping)
    const int row1 = tid >> 6, c16w = tid & 63;
    const int hw1 = row1 * 1024 + ((c16w ^ (row1 & 7)) << 4);
    const int hw2 = (row1 + 8) * 1024 + ((c16w ^ (row1 & 7)) << 4);
    const int swq = arow & 7;

    float c_st = 0.f;

    // x(0) into regs
    u32x4 xra, xrb;
    {
        const char* xt = newx + (size_t)btile * 10240;
        xra = *(const u32x4*)(xt + tid * 16);
        if (tid < 128) xrb = *(const u32x4*)(xt + 8192 + tid * 16);
    }

    for (int t = 0; t < TS; ++t) {
        // ---- 1. all waves poll the tile's 16-flag line (64B, coalesced)
        if (t > 0) {
            int spins = 0;
            for (;;) {
                unsigned f = (unsigned)t;
                if (wl < 16) f = llc_load_u32(flags + wl);
                if (__ballot(f >= (unsigned)t) == ~0ull) break;
                __builtin_amdgcn_s_sleep(2);
                if (++spins > (1 << 15)) break;   // degrade, never hang
            }
            // ---- 2. stage h(t-1): 2x16B coherent loads -> swizzled LDS
            const char* hp0 = (const char*)(hall + ((size_t)(t - 1) * 128 + btile * 16) * 512)
                              + tid * 16;
            const char* hp1 = hp0 + 8192;
            u32x4 h0, h1;
            asm volatile("global_load_dwordx4 %0, %2, off sc0 sc1\n\t"
                         "global_load_dwordx4 %1, %3, off sc0 sc1\n\t"
                         "s_waitcnt vmcnt(0)"
                         : "=&v"(h0), "=&v"(h1) : "v"(hp0), "v"(hp1) : "memory");
            *(u32x4*)(hsb + hw1) = h0;
            *(u32x4*)(hsb + hw2) = h1;
        }
        *(u32x4*)(xsb + tid * 16) = xra;
        if (tid < 128) *(u32x4*)(xsb + 8192 + tid * 16) = xrb;
        __syncthreads();   // A: stage complete

        // ---- 3. MFMA: x-projection + recurrent part
        f32x4 acc = {bb, bb, bb, bb};
        #pragma unroll
        for (int kc = 0; kc < 9; ++kc) {
            f16x8 a = *(const f16x8*)(xsb + arow * 640 + (((kc * 4 + kgrp) ^ swq) << 4));
            acc = __builtin_amdgcn_mfma_f32_16x16x32_f16(a, wi[kc], acc, 0, 0, 0);
        }
        if (t > 0) {
            f32x4 e0 = {0.f, 0.f, 0.f, 0.f}, e1 = {0.f, 0.f, 0.f, 0.f};
            #pragma unroll
            for (int kc = 0; kc < 16; kc += 2) {
                f16x8 a0 = *(const f16x8*)(hsb + arow * 1024 + (((kc * 4 + kgrp) ^ swq) << 4));
                f16x8 a1 = *(const f16x8*)(hsb + arow * 1024 + ((((kc + 1) * 4 + kgrp) ^ swq) << 4));
                e0 = __builtin_amdgcn_mfma_f32_16x16x32_f16(a0, wh[kc],     e0, 0, 0, 0);
                e1 = __builtin_amdgcn_mfma_f32_16x16x32_f16(a1, wh[kc + 1], e1, 0, 0, 0);
            }
            acc += e0; acc += e1;
        }

        // ---- 4. prefetch x(t+1) into regs (plain cached loads)
        {
            const char* xt1 = newx + ((size_t)(t + 1) * 8 + btile) * 10240;
            xra = *(const u32x4*)(xt1 + tid * 16);
            if (tid < 128) xrb = *(const u32x4*)(xt1 + 8192 + tid * 16);
        }

        // ---- 5. gates -> LDS [4][16][32] f32
        {
            float* gp = gf + g * 512 + cb * 16 + (wl & 15);
            const int b4 = (wl >> 4) * 4;
            gp[(b4 + 0) * 32] = acc[0];
            gp[(b4 + 1) * 32] = acc[1];
            gp[(b4 + 2) * 32] = acc[2];
            gp[(b4 + 3) * 32] = acc[3];
        }
        __syncthreads();   // B: gates complete

        // ---- 6. elementwise LSTM cell; h -> LDS pack buffer
        {
            const float* gq = gf + bE * 32 + colE;
            float iv = sigm_dev(gq[0]);
            float fv = sigm_dev(gq[512]);
            float gv = tanh_dev(gq[1024]);
            float ov = sigm_dev(gq[1536]);
            c_st = fv * c_st + iv * gv;
            float hv = ov * tanh_dev(c_st);
            hout[bE * 32 + colE] = (f16)hv;
        }
        __syncthreads();   // C: hout complete

        // ---- 7. wave0 packs + stores the slice (64 x 16B), acks, sets flag.
        //        Waves 1-7 run ahead to next step's poll.
        if (tid < 64) {
            u32x4 hv4 = *(const u32x4*)((const char*)hout + tid * 16);
            const f16* sp = hall + ((size_t)t * 128 + btile * 16 + (tid >> 2)) * 512
                            + hsl * 32 + (tid & 3) * 8;
            asm volatile("global_store_dwordx4 %0, %1, off sc0 sc1\n\t"
                         "s_waitcnt vmcnt(0)"
                         :: "v"(sp), "v"(hv4) : "memory");
            if (tid == 0) llc_store_nowait(myflag, (unsigned)(t + 1));
        }
    }
}

// ---------------- phase 3: out = sigmoid(h_all @ W_fc^T + b_fc) ----------------
__global__ void __launch_bounds__(256) out_gemm(const f16* __restrict__ hall,
                                                const f16* __restrict__ wfc,
                                                const float* __restrict__ bfc,
                                                float* __restrict__ out) {
    const int tid = threadIdx.x;
    const int w = tid >> 6, wl = tid & 63;
    const int arow = wl & 15, kgrp = wl >> 4;
    const long m0 = (long)blockIdx.x * 64 + w * 16;
    const f16* ap = hall + (m0 + arow) * 512 + kgrp * 8;
    f16x8 a[16];
    #pragma unroll
    for (int kc = 0; kc < 16; ++kc) a[kc] = *(const f16x8*)(ap + kc * 32);
    #pragma unroll
    for (int jt = 0; jt < 8; ++jt) {
        f32x4 acc = {0.f, 0.f, 0.f, 0.f};
        const f16* bp = wfc + (size_t)(jt * 16 + arow) * 512 + kgrp * 8;
        #pragma unroll
        for (int kc = 0; kc < 16; ++kc)
            acc = __builtin_amdgcn_mfma_f32_16x16x32_f16(a[kc], *(const f16x8*)(bp + kc * 32),
                                                         acc, 0, 0, 0);
        const int col = jt * 16 + arow;        // D col = lane&15
        if (col < 123) {
            const float bv = bfc[col];
            #pragma unroll
            for (int rr = 0; rr < 4; ++rr) {
                long m = m0 + kgrp * 4 + rr;   // D row = (lane>>4)*4 + reg
                int tt = (int)(m >> 7), b = (int)(m & 127);
                out[((size_t)b * 499 + tt) * 123 + col] = sigm_dev(acc[rr] + bv);
            }
        }
    }
}

extern "C" void kernel_launch(void* const* d_in, const int* in_sizes, int n_in,
                              void* d_out, int out_size, void* d_ws, size_t ws_size,
                              hipStream_t stream) {
    if (ws_size < WS_NEED) return;   // safe no-op rather than OOB writes

    const float* x    = (const float*)d_in[0];
    const float* W_ih = (const float*)d_in[1];
    const float* W_hh = (const float*)d_in[2];
    const float* b_ih = (const float*)d_in[3];
    const float* b_hh = (const float*)d_in[4];
    const float* W_fc = (const float*)d_in[5];
    const float* b_fc = (const float*)d_in[6];
    float* out = (float*)d_out;
    char* ws = (char*)d_ws;

    f16* newx   = (f16*)(ws + NEWX_OFF);
    f16* hall   = (f16*)(ws + HALL_OFF);
    f16* whh    = (f16*)(ws + WHH_OFF);
    f16* wih    = (f16*)(ws + WIH_OFF);
    f16* wfc    = (f16*)(ws + WFC_OFF);
    float* bias = (float*)(ws + BIAS_OFF);
    unsigned* cnt = (unsigned*)(ws + CNT_OFF);

    // flags must be 0 at the start of every call (replays don't re-poison)
    (void)hipMemsetAsync(cnt, 0, CNT_BYTES, stream);

    prep_newx<<<dim3(TS, 8), 256, 0, stream>>>(x, newx);
    prep_w<<<512, 256, 0, stream>>>(W_ih, W_hh, W_fc, b_ih, b_hh, whh, wih, wfc, bias);

    void* args[6] = {&newx, &hall, &whh, &wih, &bias, &cnt};
    (void)hipLaunchCooperativeKernel((const void*)lstm_seq, dim3(128), dim3(512), args,
                                     0, stream);

    out_gemm<<<998, 256, 0, stream>>>(hall, wfc, b_fc, out);
}